// Round 3
// baseline (1098.720 us; speedup 1.0000x reference)
//
#include <hip/hip_runtime.h>

// WeightedLoss: loss_i = (target_i == 1) ? 1 - sigmoid(pred_i) : 0.1 ; out = mean(loss)
// 1 - sigmoid(x) = 1 / (1 + exp(x))
//
// R12: grid-size / DRAM-window theory + visible probes.
//   History: fused dual-stream @2048 blocks = 3.4 TB/s (R3/R9); single-stream
//   passes (R11) = ~2.9 TB/s -> stream-count theory refuted; depth 1/2/4/8
//   plateau (R8) -> per-wave MLP not the limiter. Harness fill (write-only,
//   ~205 resident blocks, ~840 KB window) = 6.7 TB/s.
//   Theory: 2048-block grids put 8-16 MiB of addresses in flight -> per-channel
//   row-region count >> banks -> DRAM row thrash -> ~half BW. A ~4 MiB window
//   (512 blocks x 256 thr x 16B x depth-2) keeps ~one open row per bank while
//   still holding ~2.5+ MB in flight (enough for 6.6 TB/s at ~375 ns latency).
//   This round: real kernel at GRID=512; plus two 3-sweep probe kernels
//   (grid 256 / 1024, keepalive-only, >161us so they crack rocprof top-5).
//   Probes do NOT touch the output; correctness is owned by wl_main_g512.
// Predictions:
//   theory right: probe256 ~240-260us (>=6 TB/s), probe1024 ~300-350us,
//                 main kernel ~85-100us (dur arithmetic).
//   theory wrong: probes flat ~440us/3.4 TB/s; FETCH_SIZE ~3.2GB => over-fetch,
//                 ~1.6GB => true read-path ceiling.

#define BLOCK     256
#define GRID_MAIN 512    // 2 blocks/CU, 8 waves/CU, ~4 MiB in-flight window

typedef float vf4 __attribute__((ext_vector_type(4)));
typedef int   vi4 __attribute__((ext_vector_type(4)));

__device__ __forceinline__ float loss4(vf4 p, vi4 t) {
    float l0 = (t.x == 1) ? 1.0f / (1.0f + __expf(p.x)) : 0.1f;
    float l1 = (t.y == 1) ? 1.0f / (1.0f + __expf(p.y)) : 0.1f;
    float l2 = (t.z == 1) ? 1.0f / (1.0f + __expf(p.z)) : 0.1f;
    float l3 = (t.w == 1) ? 1.0f / (1.0f + __expf(p.w)) : 0.1f;
    return (l0 + l1) + (l2 + l3);
}

__device__ __forceinline__ void block_reduce_atomic(float acc, float scale,
                                                    float* __restrict__ out) {
#pragma unroll
    for (int off = 32; off > 0; off >>= 1)
        acc += __shfl_down(acc, off, 64);
    __shared__ float smem[BLOCK / 64];
    const int lane = threadIdx.x & 63;
    const int wave = threadIdx.x >> 6;
    if (lane == 0) smem[wave] = acc;
    __syncthreads();
    if (threadIdx.x == 0) {
        float bsum = (smem[0] + smem[1]) + (smem[2] + smem[3]);
        atomicAdd(out, bsum * scale);
    }
}

// ---------------- Real kernel: fused dual-stream, depth-2, GRID_MAIN ----------------
__global__ __launch_bounds__(BLOCK)
void wl_main_g512(const vf4* __restrict__ p4,
                  const vi4* __restrict__ t4,
                  float* __restrict__ out,
                  int iters, int stride, float inv_n) {
    int i = blockIdx.x * BLOCK + threadIdx.x;

    vf4 pA = __builtin_nontemporal_load(&p4[i]);
    vi4 tA = __builtin_nontemporal_load(&t4[i]);
    vf4 pB = __builtin_nontemporal_load(&p4[i + stride]);
    vi4 tB = __builtin_nontemporal_load(&t4[i + stride]);
    int idx = i + 2 * stride;

    float acc = 0.0f;
    for (int k = 0; k < iters - 2; ++k) {
        vf4 pN = __builtin_nontemporal_load(&p4[idx]);
        vi4 tN = __builtin_nontemporal_load(&t4[idx]);
        idx += stride;
        acc += loss4(pA, tA);
        pA = pB; tA = tB;
        pB = pN; tB = tN;
    }
    acc += loss4(pA, tA);
    acc += loss4(pB, tB);

    block_reduce_atomic(acc, inv_n, out);
}

// ---------------- Probes: 3 full sweeps, loads kept live, NO output ----------------
// Rule #17: asm volatile "v" keepalive prevents DCE of the probe loads.
__device__ __forceinline__ void keep8(vf4 p, vi4 t) {
    asm volatile("" :: "v"(p.x), "v"(p.y), "v"(p.z), "v"(p.w),
                       "v"(t.x), "v"(t.y), "v"(t.z), "v"(t.w));
}

__device__ __forceinline__ void probe_sweep(const vf4* __restrict__ p4,
                                            const vi4* __restrict__ t4,
                                            int iters, int stride, int i0) {
    vf4 pA = __builtin_nontemporal_load(&p4[i0]);
    vi4 tA = __builtin_nontemporal_load(&t4[i0]);
    vf4 pB = __builtin_nontemporal_load(&p4[i0 + stride]);
    vi4 tB = __builtin_nontemporal_load(&t4[i0 + stride]);
    int idx = i0 + 2 * stride;

    for (int k = 0; k < iters - 2; ++k) {
        vf4 pN = __builtin_nontemporal_load(&p4[idx]);
        vi4 tN = __builtin_nontemporal_load(&t4[idx]);
        idx += stride;
        keep8(pA, tA);
        pA = pB; tA = tB;
        pB = pN; tB = tN;
    }
    keep8(pA, tA);
    keep8(pB, tB);
}

__global__ __launch_bounds__(BLOCK)
void wl_probe_g256(const vf4* __restrict__ p4, const vi4* __restrict__ t4,
                   int iters, int stride) {
    const int i0 = blockIdx.x * BLOCK + threadIdx.x;
    for (int s = 0; s < 3; ++s)
        probe_sweep(p4, t4, iters, stride, i0);
}

__global__ __launch_bounds__(BLOCK)
void wl_probe_g1024(const vf4* __restrict__ p4, const vi4* __restrict__ t4,
                    int iters, int stride) {
    const int i0 = blockIdx.x * BLOCK + threadIdx.x;
    for (int s = 0; s < 3; ++s)
        probe_sweep(p4, t4, iters, stride, i0);
}

// ---------------- Generic fallback for arbitrary n ----------------
__global__ __launch_bounds__(BLOCK)
void wloss_generic(const float* __restrict__ pred,
                   const int*   __restrict__ tgt,
                   float* __restrict__ out,
                   long long n, float inv_n) {
    const long long n4     = n >> 2;
    const long long tid    = (long long)blockIdx.x * blockDim.x + threadIdx.x;
    const long long stride = (long long)gridDim.x * blockDim.x;

    const vf4* p4 = (const vf4*)pred;
    const vi4* t4 = (const vi4*)tgt;

    float acc = 0.0f;
    for (long long i = tid; i < n4; i += stride)
        acc += loss4(p4[i], t4[i]);
    if (blockIdx.x == 0) {
        for (long long i = (n4 << 2) + threadIdx.x; i < n; i += blockDim.x)
            acc += (tgt[i] == 1) ? 1.0f / (1.0f + __expf(pred[i])) : 0.1f;
    }
    block_reduce_atomic(acc, inv_n, out);
}

extern "C" void kernel_launch(void* const* d_in, const int* in_sizes, int n_in,
                              void* d_out, int out_size, void* d_ws, size_t ws_size,
                              hipStream_t stream) {
    const float* pred = (const float*)d_in[0];
    const int*   tgt  = (const int*)d_in[1];
    float*       out  = (float*)d_out;

    const long long n = (long long)in_sizes[0];
    const float inv_n = 1.0f / (float)n;

    hipMemsetAsync(out, 0, sizeof(float), stream);

    const long long n4 = n >> 2;
    // All three grids must divide n4 evenly; 1024*BLOCK is the coarsest.
    const long long q1024 = (long long)1024 * BLOCK;
    const bool tiled = ((n & 3) == 0) && (n4 % q1024 == 0) && (n4 / q1024 >= 3);

    if (tiled) {
        const int s512  = GRID_MAIN * BLOCK;          // 2^17 float4/step
        const int s256  = 256  * BLOCK;
        const int s1024 = 1024 * BLOCK;
        // Real computation: grid 512, ~4 MiB window.
        wl_main_g512<<<GRID_MAIN, BLOCK, 0, stream>>>(
            (const vf4*)pred, (const vi4*)tgt, out,
            (int)(n4 / s512), s512, inv_n);
        // Diagnostics (no output): 3 sweeps each => >161us => visible in top-5.
        wl_probe_g256 <<<256,  BLOCK, 0, stream>>>((const vf4*)pred, (const vi4*)tgt,
                                                   (int)(n4 / s256),  s256);
        wl_probe_g1024<<<1024, BLOCK, 0, stream>>>((const vf4*)pred, (const vi4*)tgt,
                                                   (int)(n4 / s1024), s1024);
    } else {
        long long g = (n4 + BLOCK - 1) / BLOCK;
        if (g > 8192) g = 8192;
        if (g < 1)    g = 1;
        wloss_generic<<<(int)g, BLOCK, 0, stream>>>(pred, tgt, out, n, inv_n);
    }
}

// Round 7
// 506.950 us; speedup vs baseline: 2.1673x; 2.1673x over previous
//
#include <hip/hip_runtime.h>

// WeightedLoss: loss_i = (target_i == 1) ? 1 - sigmoid(pred_i) : 0.1 ; out = mean(loss)
// 1 - sigmoid(x) = 1 / (1 + exp(x))
//
// R16 == R15 == R14 resubmitted. R13-R15 all died to "container failed twice"
//   with zero pytest/compile artifacts. Infra evidence: push_in_npz_s degraded
//   585s -> 1240s -> 1555s across the session's SUCCESSFUL rounds; the
//   failures are the continuation of that curve, at push time, before any
//   kernel executes. Kernel triple-audited for hang modes: uniform barriers
//   (loop bounds are kernel args), wave-uniform DMA dest bases + lane*16
//   fan-out == consume pattern lp[cur][tid], in-bounds indices, literal
//   size=16, 16 KiB static LDS. global_load_lds is HW-verified on MI355X in
//   exactly this shape (m97/m103/m104). Verdict: infra, not kernel.
//
// Decisive experiment: main kernel on the global_load_lds DMA path.
//   Demand reads pinned at 3.3-3.5 TB/s across grid 256/512/1024/2048, depth
//   1/2/4/8, 1-2 streams, nt on/off (R3/R8/R9/R11/R12). Fills write 6.7 TB/s.
//   R12 probe256: ~52% of read traffic L3-hit yet delivered BW still 3.9 TB/s
//   -> limiter is the demand-read RETURN path, not DRAM. global_load_lds is
//   the one untried read mechanism (no VGPR writeback; compiler never
//   auto-emits it; +67% precedent in GEMM staging m93->m97).
//   2-phase double-buffer (T3-minimum): stage k+1 -> consume k -> barrier.
// Prediction: DMA faster => kernel ~100-125us, dur ~425-450.
//             same ceiling => kernel ~160-175us, dur ~485-500 -> revert to
//             R3-exact next round and declare roofline (cross-mechanism check).

#define BLOCK 256
#define GRID  2048   // 8 blocks/CU

typedef float vf4 __attribute__((ext_vector_type(4)));
typedef int   vi4 __attribute__((ext_vector_type(4)));

typedef const __attribute__((address_space(1))) void glb_v;
typedef __attribute__((address_space(3))) void lds_v;

__device__ __forceinline__ float loss4(vf4 p, vi4 t) {
    float l0 = (t.x == 1) ? 1.0f / (1.0f + __expf(p.x)) : 0.1f;
    float l1 = (t.y == 1) ? 1.0f / (1.0f + __expf(p.y)) : 0.1f;
    float l2 = (t.z == 1) ? 1.0f / (1.0f + __expf(p.z)) : 0.1f;
    float l3 = (t.w == 1) ? 1.0f / (1.0f + __expf(p.w)) : 0.1f;
    return (l0 + l1) + (l2 + l3);
}

__device__ __forceinline__ void block_reduce_atomic(float acc, float scale,
                                                    float* __restrict__ out) {
#pragma unroll
    for (int off = 32; off > 0; off >>= 1)
        acc += __shfl_down(acc, off, 64);
    __shared__ float smem[BLOCK / 64];
    const int lane = threadIdx.x & 63;
    const int wave = threadIdx.x >> 6;
    if (lane == 0) smem[wave] = acc;
    __syncthreads();
    if (threadIdx.x == 0) {
        float bsum = (smem[0] + smem[1]) + (smem[2] + smem[3]);
        atomicAdd(out, bsum * scale);
    }
}

// ---------------- Main: DMA-staged, double-buffered, 2-phase ----------------
__global__ __launch_bounds__(BLOCK)
void wl_main_dma(const vf4* __restrict__ p4,
                 const vi4* __restrict__ t4,
                 float* __restrict__ out,
                 int iters, int stride, float inv_n) {
    // [buf 2][BLOCK] per stream: 2*2*256*16B = 16 KiB
    __shared__ vf4 lp[2][BLOCK];
    __shared__ vi4 lt[2][BLOCK];

    const int tid = threadIdx.x;
    const int wv  = tid >> 6;          // wave 0..3; DMA dest base is wave-uniform
    int idx = blockIdx.x * BLOCK + tid;

    // Prologue: stage tile 0 into buf 0.
    __builtin_amdgcn_global_load_lds((glb_v*)&p4[idx], (lds_v*)&lp[0][wv * 64], 16, 0, 0);
    __builtin_amdgcn_global_load_lds((glb_v*)&t4[idx], (lds_v*)&lt[0][wv * 64], 16, 0, 0);
    __syncthreads();                   // drains vmcnt before s_barrier

    float acc = 0.0f;
    int cur = 0;
    for (int k = 0; k < iters - 1; ++k) {
        idx += stride;
        // Issue next tile into the other buffer (in flight across consume).
        __builtin_amdgcn_global_load_lds((glb_v*)&p4[idx], (lds_v*)&lp[cur ^ 1][wv * 64], 16, 0, 0);
        __builtin_amdgcn_global_load_lds((glb_v*)&t4[idx], (lds_v*)&lt[cur ^ 1][wv * 64], 16, 0, 0);
        // Consume current tile (identity read-back: own 16B, conflict-free).
        vf4 p = lp[cur][tid];
        vi4 t = lt[cur][tid];
        acc += loss4(p, t);
        __syncthreads();               // next tile ready; reads of cur done
        cur ^= 1;
    }
    vf4 p = lp[cur][tid];
    vi4 t = lt[cur][tid];
    acc += loss4(p, t);

    block_reduce_atomic(acc, inv_n, out);
}

// ---------------- Generic fallback for arbitrary n ----------------
__global__ __launch_bounds__(BLOCK)
void wloss_generic(const float* __restrict__ pred,
                   const int*   __restrict__ tgt,
                   float* __restrict__ out,
                   long long n, float inv_n) {
    const long long n4     = n >> 2;
    const long long tid    = (long long)blockIdx.x * blockDim.x + threadIdx.x;
    const long long stride = (long long)gridDim.x * blockDim.x;

    const vf4* p4 = (const vf4*)pred;
    const vi4* t4 = (const vi4*)tgt;

    float acc = 0.0f;
    for (long long i = tid; i < n4; i += stride)
        acc += loss4(p4[i], t4[i]);
    if (blockIdx.x == 0) {
        for (long long i = (n4 << 2) + threadIdx.x; i < n; i += blockDim.x)
            acc += (tgt[i] == 1) ? 1.0f / (1.0f + __expf(pred[i])) : 0.1f;
    }
    block_reduce_atomic(acc, inv_n, out);
}

extern "C" void kernel_launch(void* const* d_in, const int* in_sizes, int n_in,
                              void* d_out, int out_size, void* d_ws, size_t ws_size,
                              hipStream_t stream) {
    const float* pred = (const float*)d_in[0];
    const int*   tgt  = (const int*)d_in[1];
    float*       out  = (float*)d_out;

    const long long n = (long long)in_sizes[0];
    const float inv_n = 1.0f / (float)n;

    hipMemsetAsync(out, 0, sizeof(float), stream);

    const long long n4 = n >> 2;
    const long long stride = (long long)GRID * BLOCK;   // 2^19 float4/step
    const bool tiled = ((n & 3) == 0) && (n4 % stride == 0) && (n4 / stride >= 2);

    if (tiled) {
        const int iters = (int)(n4 / stride);           // 32 for N=2^26
        wl_main_dma<<<GRID, BLOCK, 0, stream>>>((const vf4*)pred,
                                                (const vi4*)tgt, out,
                                                iters, (int)stride, inv_n);
    } else {
        long long g = (n4 + BLOCK - 1) / BLOCK;
        if (g > 8192) g = 8192;
        if (g < 1)    g = 1;
        wloss_generic<<<(int)g, BLOCK, 0, stream>>>(pred, tgt, out, n, inv_n);
    }
}

// Round 8
// 503.702 us; speedup vs baseline: 2.1813x; 1.0064x over previous
//
#include <hip/hip_runtime.h>

// WeightedLoss: loss_i = (target_i == 1) ? 1 - sigmoid(pred_i) : 0.1 ; out = mean(loss)
// 1 - sigmoid(x) = 1 / (1 + exp(x))
//
// R17: revert to R3-exact (best-known, 481.2us) — roofline reached.
//   Session conclusion: demand-read ceiling ~3.4 TB/s on this chip.
//   - demand dual-stream loads: 3.3-3.5 TB/s (grid 256/512/1024/2048,
//     depth 1/2/4/8, nt on/off — R3/R8/R9/R12)
//   - demand single-stream: ~2.9 TB/s (R11)
//   - global_load_lds DMA double-buffer: ~2.9 TB/s (R16, cross-mechanism check)
//   - writes (harness fills): 6.7 TB/s  -> DRAM itself has headroom; cap is
//     the chip-level read return path.
//   - m13 copy ubench 6.29 TB/s = R+W -> read component ~3.15 TB/s; we exceed it.
//   - R12: ~52% L3-hit traffic, BW still capped -> no locality trick applies.
//   Floor: 512 MiB read / 3.4 TB/s ~ 158us; this kernel ~157us. At roofline.
//   Remaining dur_us (~322us) is harness re-poison fills, outside our control.

#define BLOCK 256
#define GRID  2048   // 8 blocks/CU — best measured config

typedef float vf4 __attribute__((ext_vector_type(4)));
typedef int   vi4 __attribute__((ext_vector_type(4)));

__device__ __forceinline__ float loss4(vf4 p, vi4 t) {
    float l0 = (t.x == 1) ? 1.0f / (1.0f + __expf(p.x)) : 0.1f;
    float l1 = (t.y == 1) ? 1.0f / (1.0f + __expf(p.y)) : 0.1f;
    float l2 = (t.z == 1) ? 1.0f / (1.0f + __expf(p.z)) : 0.1f;
    float l3 = (t.w == 1) ? 1.0f / (1.0f + __expf(p.w)) : 0.1f;
    return (l0 + l1) + (l2 + l3);
}

__device__ __forceinline__ void block_reduce_atomic(float acc, float scale,
                                                    float* __restrict__ out) {
#pragma unroll
    for (int off = 32; off > 0; off >>= 1)
        acc += __shfl_down(acc, off, 64);
    __shared__ float smem[BLOCK / 64];
    const int lane = threadIdx.x & 63;
    const int wave = threadIdx.x >> 6;
    if (lane == 0) smem[wave] = acc;
    __syncthreads();
    if (threadIdx.x == 0) {
        float bsum = (smem[0] + smem[1]) + (smem[2] + smem[3]);
        atomicAdd(out, bsum * scale);
    }
}

// ---------------- Main: R3-exact fused dual-stream, depth-2 pipeline ----------------
__global__ __launch_bounds__(BLOCK)
void wl_main(const vf4* __restrict__ p4,
             const vi4* __restrict__ t4,
             float* __restrict__ out,
             int iters, int stride, float inv_n) {
    int i = blockIdx.x * BLOCK + threadIdx.x;

    vf4 pA = p4[i];
    vi4 tA = t4[i];
    vf4 pB = p4[i + stride];
    vi4 tB = t4[i + stride];
    int idx = i + 2 * stride;

    float acc = 0.0f;
    for (int k = 0; k < iters - 2; ++k) {
        vf4 pN = p4[idx];
        vi4 tN = t4[idx];
        idx += stride;
        acc += loss4(pA, tA);
        pA = pB; tA = tB;
        pB = pN; tB = tN;
    }
    acc += loss4(pA, tA);
    acc += loss4(pB, tB);

    block_reduce_atomic(acc, inv_n, out);
}

// ---------------- Generic fallback for arbitrary n ----------------
__global__ __launch_bounds__(BLOCK)
void wloss_generic(const float* __restrict__ pred,
                   const int*   __restrict__ tgt,
                   float* __restrict__ out,
                   long long n, float inv_n) {
    const long long n4     = n >> 2;
    const long long tid    = (long long)blockIdx.x * blockDim.x + threadIdx.x;
    const long long stride = (long long)gridDim.x * blockDim.x;

    const vf4* p4 = (const vf4*)pred;
    const vi4* t4 = (const vi4*)tgt;

    float acc = 0.0f;
    for (long long i = tid; i < n4; i += stride)
        acc += loss4(p4[i], t4[i]);
    if (blockIdx.x == 0) {
        for (long long i = (n4 << 2) + threadIdx.x; i < n; i += blockDim.x)
            acc += (tgt[i] == 1) ? 1.0f / (1.0f + __expf(pred[i])) : 0.1f;
    }
    block_reduce_atomic(acc, inv_n, out);
}

extern "C" void kernel_launch(void* const* d_in, const int* in_sizes, int n_in,
                              void* d_out, int out_size, void* d_ws, size_t ws_size,
                              hipStream_t stream) {
    const float* pred = (const float*)d_in[0];
    const int*   tgt  = (const int*)d_in[1];
    float*       out  = (float*)d_out;

    const long long n = (long long)in_sizes[0];
    const float inv_n = 1.0f / (float)n;

    hipMemsetAsync(out, 0, sizeof(float), stream);

    const long long n4 = n >> 2;
    const long long stride = (long long)GRID * BLOCK;   // 2^19 float4/step
    const bool tiled = ((n & 3) == 0) && (n4 % stride == 0) && (n4 / stride >= 3);

    if (tiled) {
        const int iters = (int)(n4 / stride);           // 32 for N=2^26
        wl_main<<<GRID, BLOCK, 0, stream>>>((const vf4*)pred,
                                            (const vi4*)tgt, out,
                                            iters, (int)stride, inv_n);
    } else {
        long long g = (n4 + BLOCK - 1) / BLOCK;
        if (g > 8192) g = 8192;
        if (g < 1)    g = 1;
        wloss_generic<<<(int)g, BLOCK, 0, stream>>>(pred, tgt, out, n, inv_n);
    }
}